// Round 5
// baseline (460.121 us; speedup 1.0000x reference)
//
#include <hip/hip_runtime.h>
#include <hip/hip_bf16.h>
#include <math.h>

#define N_NODES 50000
#define N_EDGES 1600000
#define N_GRAPHS 64
#define N_PART 8
#define SLOT_P 32          // per-(node,partition) capacity; Binom(32,1/8) > 32: P~7e-17
#define ROW_STRIDE 80      // per-node row capacity; Poisson(32) > 80: P~5e-13

// ---------------------------------------------------------------------------
// DPP cross-lane add helpers (VALU pipe, no LDS).
// ---------------------------------------------------------------------------
template <int CTRL>
__device__ __forceinline__ float dpp_add(float v) {
    int r = __builtin_amdgcn_update_dpp(0, __builtin_bit_cast(int, v), CTRL, 0xF, 0xF, true);
    return v + __builtin_bit_cast(float, r);
}

__device__ __forceinline__ float red16(float v) {
    v = dpp_add<0xB1>(v);    // quad_perm [1,0,3,2]
    v = dpp_add<0x4E>(v);    // quad_perm [2,3,0,1]
    v = dpp_add<0x141>(v);   // row_half_mirror
    v = dpp_add<0x140>(v);   // row_mirror
    return v;
}

__device__ __forceinline__ float edge_ev_l1(float xlv, float xrn, float attv) {
    float u = xlv + xrn;
    u = u > 0.f ? u : 0.2f * u;
    float v = red16(attv * u);
    v += __shfl_xor(v, 16);
    return __expf(v);
}

__device__ __forceinline__ float edge_ev_l2(float xlv, float xrn, float attv) {
    float u = xlv + xrn;
    u = u > 0.f ? u : 0.2f * u;
    float v = red16(attv * u);
    v += __shfl_xor(v, 16);
    v += __shfl_xor(v, 32);
    return __expf(v);
}

// ---------------------------------------------------------------------------
// Register-tiled dense transform: out = x @ [Wl | Wr].
// Block = 64 nodes, 4 waves; lane = node, wave = 32-col group; W rows are
// wave-uniform -> scalar loads; 32 independent accumulators break dep chains.
// ---------------------------------------------------------------------------
template <int K>
__global__ __launch_bounds__(256) void gemm_tiled(
    const float* __restrict__ x, const float* __restrict__ Wl,
    const float* __restrict__ Wr, float* __restrict__ xl, float* __restrict__ xr) {
    __shared__ float xs[64][K + 1];
    const int t = threadIdx.x;
    const int base = blockIdx.x * 64;
    const int nf4 = 64 * K / 4;
    for (int f = t; f < nf4; f += 256) {
        const int row = f / (K / 4);
        const int c4 = f % (K / 4);
        float4 v = make_float4(0.f, 0.f, 0.f, 0.f);
        if (base + row < N_NODES)
            v = *(const float4*)(x + (size_t)(base + row) * K + c4 * 4);
        xs[row][c4 * 4 + 0] = v.x;
        xs[row][c4 * 4 + 1] = v.y;
        xs[row][c4 * 4 + 2] = v.z;
        xs[row][c4 * 4 + 3] = v.w;
    }
    __syncthreads();
    const int lane = t & 63;
    const int w = __builtin_amdgcn_readfirstlane(t >> 6);
    const float* __restrict__ W = (w < 2) ? Wl : Wr;
    const int cb = (w & 1) * 32;
    float acc[32];
#pragma unroll
    for (int j = 0; j < 32; ++j) acc[j] = 0.f;
#pragma unroll 2
    for (int k = 0; k < K; ++k) {
        const float xv = xs[lane][k];
        const float* __restrict__ Wrow = W + k * 64 + cb;
#pragma unroll
        for (int j = 0; j < 32; ++j) acc[j] = fmaf(xv, Wrow[j], acc[j]);
    }
    const int n = base + lane;
    if (n < N_NODES) {
        float* __restrict__ o = (w < 2) ? xl : xr;
#pragma unroll
        for (int j = 0; j < 32; j += 4) {
            float4 v = {acc[j], acc[j + 1], acc[j + 2], acc[j + 3]};
            *(float4*)(o + (size_t)n * 64 + cb + j) = v;
        }
    }
}

// ---------------------------------------------------------------------------
// Partitioned adjacency build (fused hist+scatter, no scan needed).
// Partition p = blockIdx&7: with round-robin block->XCD dispatch each
// partition's slot region is written by a single XCD (L2-local, no
// cross-XCD line ping-pong). Correct regardless of actual mapping.
// ---------------------------------------------------------------------------
__global__ __launch_bounds__(256) void build_kernel(
    const int* __restrict__ ei, int* __restrict__ deg8, int* __restrict__ slots8) {
    const int e = blockIdx.x * 256 + threadIdx.x;
    if (e >= N_EDGES) return;
    const int p = blockIdx.x & (N_PART - 1);
    const int d = ei[N_EDGES + e];
    const int cell = p * N_NODES + d;
    const int pos = atomicAdd(&deg8[cell], 1);
    if (pos < SLOT_P) slots8[cell * SLOT_P + pos] = ei[e];
}

// Concatenate the 8 partition rows of each node into one stride-80 row,
// fully coalesced writes; also emits deg[n]. One wave per node.
__global__ __launch_bounds__(256) void compact_kernel(
    const int* __restrict__ deg8, const int* __restrict__ slots8,
    int* __restrict__ deg, int* __restrict__ rows) {
    const int n = (blockIdx.x * 256 + threadIdx.x) >> 6;
    const int lane = threadIdx.x & 63;
    if (n >= N_NODES) return;
    int offs[N_PART + 1];
    int off = 0;
#pragma unroll
    for (int p = 0; p < N_PART; ++p) {
        offs[p] = off;
        int c = deg8[p * N_NODES + n];
        off += (c < SLOT_P ? c : SLOT_P);
    }
    offs[N_PART] = off;
    int total = off < ROW_STRIDE ? off : ROW_STRIDE;
    if (lane == 0) deg[n] = total;
    for (int j = lane; j < total; j += 64) {
        int addr = n * SLOT_P + j;   // partition 0: (0*N+n)*SLOT_P + (j-0)
#pragma unroll
        for (int q = 1; q < N_PART; ++q) {
            int aq = (q * N_NODES + n) * SLOT_P + (j - offs[q]);
            addr = (j >= offs[q]) ? aq : addr;
        }
        rows[n * ROW_STRIDE + j] = slots8[addr];
    }
}

// ---------------------------------------------------------------------------
// Node-centric GATv2 layer: one wave per dst node, x4 unrolled ILP chains.
// ---------------------------------------------------------------------------
__global__ __launch_bounds__(256) void node_l1(
    const int* __restrict__ deg, const int* __restrict__ rows,
    const float* __restrict__ xl, const float* __restrict__ xr,
    const float* __restrict__ att, const float* __restrict__ b1,
    float* __restrict__ h1) {
    const int n = (blockIdx.x * 256 + threadIdx.x) >> 6;
    const int lane = threadIdx.x & 63;
    const float xrn = xr[n * 64 + lane];
    const float xln = xl[n * 64 + lane];
    const float attv = att[lane];
    float ev = edge_ev_l1(xln, xrn, attv);   // self loop
    float accv = ev * xln;
    float ssum = ev;
    const int cnt = __builtin_amdgcn_readfirstlane(deg[n]);
    const int* __restrict__ row = rows + n * ROW_STRIDE;
    int i = 0;
    for (; i + 3 < cnt; i += 4) {
        const int s0 = row[i + 0];
        const int s1 = row[i + 1];
        const int s2 = row[i + 2];
        const int s3 = row[i + 3];
        const float a0 = xl[s0 * 64 + lane];
        const float a1 = xl[s1 * 64 + lane];
        const float a2 = xl[s2 * 64 + lane];
        const float a3 = xl[s3 * 64 + lane];
        const float e0 = edge_ev_l1(a0, xrn, attv);
        const float e1 = edge_ev_l1(a1, xrn, attv);
        const float e2 = edge_ev_l1(a2, xrn, attv);
        const float e3 = edge_ev_l1(a3, xrn, attv);
        accv = fmaf(e0, a0, accv);
        accv = fmaf(e1, a1, accv);
        accv = fmaf(e2, a2, accv);
        accv = fmaf(e3, a3, accv);
        ssum += (e0 + e1) + (e2 + e3);
    }
    for (; i < cnt; ++i) {
        const int src = row[i];
        const float xlv = xl[src * 64 + lane];
        const float e2 = edge_ev_l1(xlv, xrn, attv);
        accv = fmaf(e2, xlv, accv);
        ssum += e2;
    }
    float o = accv / (ssum + 1e-16f) + b1[lane];
    h1[n * 64 + lane] = o > 0.f ? o : expm1f(o);
}

__global__ __launch_bounds__(256) void node_l2(
    const int* __restrict__ deg, const int* __restrict__ rows,
    const float* __restrict__ xl, const float* __restrict__ xr,
    const float* __restrict__ att, const float* __restrict__ b2,
    float* __restrict__ h2) {
    const int n = (blockIdx.x * 256 + threadIdx.x) >> 6;
    const int lane = threadIdx.x & 63;
    const float xrn = xr[n * 64 + lane];
    const float xln = xl[n * 64 + lane];
    const float attv = att[lane];
    float ev = edge_ev_l2(xln, xrn, attv);
    float accv = ev * xln;
    float ssum = ev;
    const int cnt = __builtin_amdgcn_readfirstlane(deg[n]);
    const int* __restrict__ row = rows + n * ROW_STRIDE;
    int i = 0;
    for (; i + 3 < cnt; i += 4) {
        const int s0 = row[i + 0];
        const int s1 = row[i + 1];
        const int s2 = row[i + 2];
        const int s3 = row[i + 3];
        const float a0 = xl[s0 * 64 + lane];
        const float a1 = xl[s1 * 64 + lane];
        const float a2 = xl[s2 * 64 + lane];
        const float a3 = xl[s3 * 64 + lane];
        const float e0 = edge_ev_l2(a0, xrn, attv);
        const float e1 = edge_ev_l2(a1, xrn, attv);
        const float e2 = edge_ev_l2(a2, xrn, attv);
        const float e3 = edge_ev_l2(a3, xrn, attv);
        accv = fmaf(e0, a0, accv);
        accv = fmaf(e1, a1, accv);
        accv = fmaf(e2, a2, accv);
        accv = fmaf(e3, a3, accv);
        ssum += (e0 + e1) + (e2 + e3);
    }
    for (; i < cnt; ++i) {
        const int src = row[i];
        const float xlv = xl[src * 64 + lane];
        const float e2 = edge_ev_l2(xlv, xrn, attv);
        accv = fmaf(e2, xlv, accv);
        ssum += e2;
    }
    float o = accv / (ssum + 1e-16f) + b2[lane];
    h2[n * 64 + lane] = o > 0.f ? o : expm1f(o);
}

// Mean-pool accumulation over sorted batch ids.
__global__ __launch_bounds__(64) void pool_kernel(
    const float* __restrict__ h2, const int* __restrict__ batch,
    float* __restrict__ pooled, float* __restrict__ cnt) {
    const int t = threadIdx.x;
    const int base = blockIdx.x * 64;
    float local = 0.f, lc = 0.f;
    int cur = -1;
    for (int j = 0; j < 64; ++j) {
        const int n = base + j;
        if (n >= N_NODES) break;
        const int g = batch[n];
        if (g != cur) {
            if (cur >= 0) {
                unsafeAtomicAdd(&pooled[cur * 64 + t], local);
                if (t == 0) unsafeAtomicAdd(&cnt[cur], lc);
            }
            cur = g; local = 0.f; lc = 0.f;
        }
        local += h2[n * 64 + t];
        lc += 1.f;
    }
    if (cur >= 0) {
        unsafeAtomicAdd(&pooled[cur * 64 + t], local);
        if (t == 0) unsafeAtomicAdd(&cnt[cur], lc);
    }
}

__global__ __launch_bounds__(128) void head_kernel(
    const float* __restrict__ pooled, const float* __restrict__ cnt,
    const float* __restrict__ lin_w, const float* __restrict__ lin_b,
    float* __restrict__ out) {
    const int i = threadIdx.x;          // 0..127 -> (g, k)
    const int g = i >> 1, k = i & 1;
    float c = cnt[g];
    c = c > 1.f ? c : 1.f;
    float a = 0.f;
#pragma unroll
    for (int j = 0; j < 64; ++j) a = fmaf(pooled[g * 64 + j] / c, lin_w[j * 2 + k], a);
    out[i] = a + lin_b[k];
}

extern "C" void kernel_launch(void* const* d_in, const int* in_sizes, int n_in,
                              void* d_out, int out_size, void* d_ws, size_t ws_size,
                              hipStream_t stream) {
    const float* x     = (const float*)d_in[0];
    const int*   ei    = (const int*)d_in[1];
    const int*   batch = (const int*)d_in[2];
    const float* Wl1   = (const float*)d_in[3];
    const float* Wr1   = (const float*)d_in[4];
    const float* att1  = (const float*)d_in[5];
    const float* b1    = (const float*)d_in[6];
    const float* Wl2   = (const float*)d_in[7];
    const float* Wr2   = (const float*)d_in[8];
    const float* att2  = (const float*)d_in[9];
    const float* b2    = (const float*)d_in[10];
    const float* lin_w = (const float*)d_in[11];
    const float* lin_b = (const float*)d_in[12];

    float* ws = (float*)d_ws;
    float* xl     = ws;                          //  3,200,000
    float* xr     = ws + 3200000;                //  3,200,000
    float* h1     = ws + 6400000;                //  3,200,000 (reused as h2)
    int*   rows   = (int*)(ws + 9600000);        //  4,000,000 (50000*80)
    int*   deg    = (int*)(ws + 13600000);       //     50,000
    int*   deg8   = (int*)(ws + 13650000);       //    400,000  -- memset start
    float* pooled = ws + 14050000;               //      4,096
    float* cnt    = ws + 14054096;               //         64
    int*   slots8 = (int*)(ws + 14054160);       // 12,800,000 (8*50000*32)
    // total 26,854,160 floats ~= 107.4 MB (ws is 256 MiB)

    // zero deg8 + pooled + cnt (contiguous)
    hipMemsetAsync(deg8, 0, (size_t)(400000 + 4096 + 64) * sizeof(float), stream);

    // ---- adjacency build: partitioned count+scatter, then compaction ----
    build_kernel<<<(N_EDGES + 255) / 256, 256, 0, stream>>>(ei, deg8, slots8);
    compact_kernel<<<(N_NODES + 3) / 4, 256, 0, stream>>>(deg8, slots8, deg, rows);

    const int gblocks = (N_NODES + 63) / 64;   // 782

    // ---- layer 1 ----
    gemm_tiled<128><<<gblocks, 256, 0, stream>>>(x, Wl1, Wr1, xl, xr);
    node_l1<<<N_NODES / 4, 256, 0, stream>>>(deg, rows, xl, xr, att1, b1, h1);

    // ---- layer 2 (h2 reuses h1 buffer; gemm consumed h1 first) ----
    gemm_tiled<64><<<gblocks, 256, 0, stream>>>(h1, Wl2, Wr2, xl, xr);
    node_l2<<<N_NODES / 4, 256, 0, stream>>>(deg, rows, xl, xr, att2, b2, h1);

    // ---- pool + head ----
    pool_kernel<<<(N_NODES + 63) / 64, 64, 0, stream>>>(h1, batch, pooled, cnt);
    head_kernel<<<1, 128, 0, stream>>>(pooled, cnt, lin_w, lin_b, (float*)d_out);
}